// Round 8
// baseline (41.260 us; speedup 1.0000x reference)
//
#include <hip/hip_runtime.h>

// out[z, k] = sum_{n in segment(k)} vals[n] * x1[z, i_idx[n]] * x2[z, j_idx[n]]
//
// Structure facts (verified over R3-R7):
//  * every output row k is ONE contiguous run in n (runs NOT ascending in k;
//    per-k seg_start/seg_end required; row_ptr CSR is wrong — R4 failure)
//  * every k appears => boundary detection fully populates bounds
//
// R8: overlap fix via vmcnt ordering. vmcnt is ONE per-wave counter shared by
// loads and stores, strictly ordered. If stage loads for gen g+1 are issued
// AFTER gen g's stores (R3/R5/R6 order), the wait for stage data drains the
// stores -> phases serialize (measured: time == pipe SUM every round).
// Fix: persistent 4-generation blocks; per gen issue stage-LOADS(g+1) FIRST,
// then gather(g), then stores(g) (younger than the loads), barrier, ds_write
// (waits only the older loads), barrier. Stores drain under next gather.
// ZPT=8 keeps VGPR low (32 waves/CU), BLK=256, LDS 13.8KB.

#define ZPT 8
#define BLK 256
#define DIM_IN 144
#define NQ (DIM_IN / 4)            // 36 float4 per row
#define N4 (ZPT * NQ)              // 288 float4 slots per array per gen
#define STRIDE 12                  // dwords; mult of 4 (b128-aligned), 8 bank groups
#define GENS 4
#define GRID_Y 32                  // 128 z-groups / GENS

__global__ void prep_kernel(const int* __restrict__ k_idx,
                            const float* __restrict__ vals,
                            const int* __restrict__ i_idx,
                            const int* __restrict__ j_idx,
                            int nnz,
                            int* __restrict__ seg_start,
                            int* __restrict__ seg_end,
                            int2* __restrict__ packed) {
    int n = blockIdx.x * blockDim.x + threadIdx.x;
    if (n >= nnz) return;
    int k = k_idx[n];
    if (n == 0 || k_idx[n - 1] != k) seg_start[k] = n;
    if (n == nnz - 1 || k_idx[n + 1] != k) seg_end[k] = n + 1;
    packed[n] = make_int2(i_idx[n] | (j_idx[n] << 16), __float_as_int(vals[n]));
}

__device__ __forceinline__ void lds_write_t(float* dst, int i4, int t,
                                            const float4& v) {
    const int base = i4 * 4 * STRIDE + t;
    dst[base             ] = v.x;
    dst[base +     STRIDE] = v.y;
    dst[base + 2 * STRIDE] = v.z;
    dst[base + 3 * STRIDE] = v.w;
}

__global__ __launch_bounds__(BLK) void tp_kernel(
        const float* __restrict__ x1,
        const float* __restrict__ x2,
        const int2* __restrict__ packed,
        const int* __restrict__ seg_start,
        const int* __restrict__ seg_end,
        float* __restrict__ out,
        int dim_out) {
    __shared__ __align__(16) float x1s[DIM_IN * STRIDE];
    __shared__ __align__(16) float x2s[DIM_IN * STRIDE];

    const int tid = threadIdx.x;
    const int k   = blockIdx.x * BLK + tid;
    const bool live = (k < dim_out);

    int s = 0, e = 0;
    if (live) {
        s = seg_start[k];
        e = seg_end[k];
    }

    // staging slots: slot0 = tid (all threads), slot1 = tid+BLK (tid < 32)
    const int t0 = tid / NQ,        i40 = tid % NQ;
    const int t1 = (tid + BLK) / NQ, i41 = (tid + BLK) % NQ;
    const bool has1 = (tid + BLK) < N4;

    const int zg0 = blockIdx.y * GENS;

    // ---- prologue: stage generation 0 (no stores outstanding yet) ----
    {
        const int z0 = zg0 * ZPT;
        float4 A0 = *(const float4*)(x1 + (size_t)(z0 + t0) * DIM_IN + i40 * 4);
        float4 B0 = *(const float4*)(x2 + (size_t)(z0 + t0) * DIM_IN + i40 * 4);
        float4 A1, B1;
        if (has1) {
            A1 = *(const float4*)(x1 + (size_t)(z0 + t1) * DIM_IN + i41 * 4);
            B1 = *(const float4*)(x2 + (size_t)(z0 + t1) * DIM_IN + i41 * 4);
        }
        lds_write_t(x1s, i40, t0, A0);
        lds_write_t(x2s, i40, t0, B0);
        if (has1) {
            lds_write_t(x1s, i41, t1, A1);
            lds_write_t(x2s, i41, t1, B1);
        }
    }
    __syncthreads();

#pragma unroll
    for (int gen = 0; gen < GENS; ++gen) {
        const int z0 = (zg0 + gen) * ZPT;
        const bool more_gen = (gen + 1 < GENS);

        // (A) issue stage loads for NEXT gen FIRST (older than this gen's
        //     stores in vmcnt order -> waiting for these never drains stores)
        float4 nA0, nB0, nA1, nB1;
        if (more_gen) {
            const int nz0 = z0 + ZPT;
            nA0 = *(const float4*)(x1 + (size_t)(nz0 + t0) * DIM_IN + i40 * 4);
            nB0 = *(const float4*)(x2 + (size_t)(nz0 + t0) * DIM_IN + i40 * 4);
            if (has1) {
                nA1 = *(const float4*)(x1 + (size_t)(nz0 + t1) * DIM_IN + i41 * 4);
                nB1 = *(const float4*)(x2 + (size_t)(nz0 + t1) * DIM_IN + i41 * 4);
            }
        }

        // (B) gather from LDS (software-pipelined entry loop)
        float acc[ZPT];
#pragma unroll
        for (int t = 0; t < ZPT; ++t) acc[t] = 0.0f;

        if (live) {
            int n = s;
            if (n < e) {
                int2 ev = packed[n];
                for (;;) {
                    const bool more = (n + 1 < e);
                    int2 evn;
                    if (more) evn = packed[n + 1];

                    const float c = __int_as_float(ev.y);
                    const int i = ev.x & 0xffff;
                    const int j = ev.x >> 16;
                    const float4* p1 = (const float4*)(x1s + i * STRIDE);
                    const float4* p2 = (const float4*)(x2s + j * STRIDE);
#pragma unroll
                    for (int q = 0; q < ZPT / 4; ++q) {
                        const float4 a = p1[q];
                        const float4 b = p2[q];
                        acc[4 * q + 0] += c * a.x * b.x;
                        acc[4 * q + 1] += c * a.y * b.y;
                        acc[4 * q + 2] += c * a.z * b.z;
                        acc[4 * q + 3] += c * a.w * b.w;
                    }

                    ++n;
                    if (!more) break;
                    ev = evn;
                }
            }

            // (C) stores — younger than the (A) loads; stay in flight
#pragma unroll
            for (int t = 0; t < ZPT; ++t) {
                out[(size_t)(z0 + t) * dim_out + k] = acc[t];
            }
        }

        // (D) all waves done reading the buffer
        __syncthreads();

        // (E) ds_write next gen: its vmcnt wait covers only the (A) loads
        if (more_gen) {
            lds_write_t(x1s, i40, t0, nA0);
            lds_write_t(x2s, i40, t0, nB0);
            if (has1) {
                lds_write_t(x1s, i41, t1, nA1);
                lds_write_t(x2s, i41, t1, nB1);
            }
            // (F) buffer ready
            __syncthreads();
        }
    }
}

extern "C" void kernel_launch(void* const* d_in, const int* in_sizes, int n_in,
                              void* d_out, int out_size, void* d_ws, size_t ws_size,
                              hipStream_t stream) {
    const float* x1   = (const float*)d_in[0];
    const float* x2   = (const float*)d_in[1];
    const float* vals = (const float*)d_in[2];
    const int*   kidx = (const int*)d_in[3];
    const int*   iidx = (const int*)d_in[4];
    const int*   jidx = (const int*)d_in[5];
    float* out = (float*)d_out;

    const int n_batch = 1024;                  // N_BATCH in the reference
    const int dim_out = out_size / n_batch;    // 20736
    const int nnz     = in_sizes[2];

    // workspace: seg_start[dim_out], seg_end[dim_out], packed int2[nnz]
    int*  seg_start = (int*)d_ws;
    int*  seg_end   = seg_start + dim_out;
    int2* packed    = (int2*)(seg_end + dim_out);   // 8B-aligned

    {
        int grid = (nnz + 255) / 256;
        prep_kernel<<<grid, 256, 0, stream>>>(kidx, vals, iidx, jidx, nnz,
                                              seg_start, seg_end, packed);
    }

    {
        dim3 grid((dim_out + BLK - 1) / BLK, GRID_Y);
        tp_kernel<<<grid, BLK, 0, stream>>>(x1, x2, packed,
                                            seg_start, seg_end, out, dim_out);
    }
}